// Round 6
// baseline (4798.984 us; speedup 1.0000x reference)
//
#include <hip/hip_runtime.h>
#include <hip/hip_bf16.h>
#include <stdint.h>

#define L_SEQ 2048
#define BATCH 32
#define D_IN 1024
#define DENSE 256
#define HID 128
#define GATES 512   // 4*HID
#define NT 4
#define START_TAG 2
#define STOP_TAG 3
#define IMPOSSIBLE -10000.0f

// ---------------------------------------------------------------------------
// Tiled fp32 GEMM:  C[M,N] = act(A[M,K] * Bw[N,K]^T + bias1[n] (+ bias2[n]))
// 128x128 tile, BK=16, 256 threads, 8x8 microtile, double-buffered ping-pong,
// one barrier per K-tile. NOTE: no address-of on local arrays (a/b filled
// element-wise from float4 LDS reads) so they stay in VGPRs.
// ---------------------------------------------------------------------------
template<bool RELU, bool DUAL>
__global__ __launch_bounds__(256)
void gemm_nt(const float* __restrict__ A, const float* __restrict__ Bw,
             const float* __restrict__ b1, const float* __restrict__ b2,
             float* __restrict__ C, int M, int N, int K)
{
    __shared__ __align__(16) float As[2][16][132];
    __shared__ __align__(16) float Bs[2][16][132];

    const int tid = threadIdx.x;
    const int tx = tid & 15;        // 0..15  -> N direction
    const int ty = tid >> 4;        // 0..15  -> M direction
    const int m0 = blockIdx.x * 128;
    const int n0 = blockIdx.y * 128;

    const int lrow = tid >> 2;          // 0..63
    const int lcol = (tid & 3) * 4;     // 0,4,8,12

    const float* aptr = &A[(size_t)(m0 + lrow) * K + lcol];
    const float* bptr = &Bw[(size_t)(n0 + lrow) * K + lcol];
    const size_t rstride = (size_t)64 * K;

    float acc[8][8];
#pragma unroll
    for (int i = 0; i < 8; ++i)
#pragma unroll
        for (int j = 0; j < 8; ++j) acc[i][j] = 0.f;

    // prologue: stage tile 0 into buf 0
    {
        float4 a0 = *(const float4*)(aptr);
        float4 a1 = *(const float4*)(aptr + rstride);
        float4 v0 = *(const float4*)(bptr);
        float4 v1 = *(const float4*)(bptr + rstride);
        As[0][lcol + 0][lrow] = a0.x; As[0][lcol + 1][lrow] = a0.y;
        As[0][lcol + 2][lrow] = a0.z; As[0][lcol + 3][lrow] = a0.w;
        As[0][lcol + 0][lrow + 64] = a1.x; As[0][lcol + 1][lrow + 64] = a1.y;
        As[0][lcol + 2][lrow + 64] = a1.z; As[0][lcol + 3][lrow + 64] = a1.w;
        Bs[0][lcol + 0][lrow] = v0.x; Bs[0][lcol + 1][lrow] = v0.y;
        Bs[0][lcol + 2][lrow] = v0.z; Bs[0][lcol + 3][lrow] = v0.w;
        Bs[0][lcol + 0][lrow + 64] = v1.x; Bs[0][lcol + 1][lrow + 64] = v1.y;
        Bs[0][lcol + 2][lrow + 64] = v1.z; Bs[0][lcol + 3][lrow + 64] = v1.w;
    }
    __syncthreads();

    int buf = 0;
    for (int k0 = 0; k0 < K; k0 += 16) {
        // issue next-tile loads NOW (redundant reload of last tile: harmless)
        const int kn = (k0 + 16 < K) ? (k0 + 16) : k0;
        float4 na0 = *(const float4*)(aptr + kn);
        float4 na1 = *(const float4*)(aptr + kn + rstride);
        float4 nb0 = *(const float4*)(bptr + kn);
        float4 nb1 = *(const float4*)(bptr + kn + rstride);

        // compute on current buffer (latency of na*/nb* hides under this)
#pragma unroll
        for (int kk = 0; kk < 16; ++kk) {
            float4 av0 = *(const float4*)&As[buf][kk][ty * 8];
            float4 av1 = *(const float4*)&As[buf][kk][ty * 8 + 4];
            float4 bv0 = *(const float4*)&Bs[buf][kk][tx * 8];
            float4 bv1 = *(const float4*)&Bs[buf][kk][tx * 8 + 4];
            float a[8], b[8];
            a[0] = av0.x; a[1] = av0.y; a[2] = av0.z; a[3] = av0.w;
            a[4] = av1.x; a[5] = av1.y; a[6] = av1.z; a[7] = av1.w;
            b[0] = bv0.x; b[1] = bv0.y; b[2] = bv0.z; b[3] = bv0.w;
            b[4] = bv1.x; b[5] = bv1.y; b[6] = bv1.z; b[7] = bv1.w;
#pragma unroll
            for (int i = 0; i < 8; ++i)
#pragma unroll
                for (int j = 0; j < 8; ++j)
                    acc[i][j] = fmaf(a[i], b[j], acc[i][j]);
        }

        // stage next tile into the other buffer (vmcnt drain lands here)
        const int nb = buf ^ 1;
        As[nb][lcol + 0][lrow] = na0.x; As[nb][lcol + 1][lrow] = na0.y;
        As[nb][lcol + 2][lrow] = na0.z; As[nb][lcol + 3][lrow] = na0.w;
        As[nb][lcol + 0][lrow + 64] = na1.x; As[nb][lcol + 1][lrow + 64] = na1.y;
        As[nb][lcol + 2][lrow + 64] = na1.z; As[nb][lcol + 3][lrow + 64] = na1.w;
        Bs[nb][lcol + 0][lrow] = nb0.x; Bs[nb][lcol + 1][lrow] = nb0.y;
        Bs[nb][lcol + 2][lrow] = nb0.z; Bs[nb][lcol + 3][lrow] = nb0.w;
        Bs[nb][lcol + 0][lrow + 64] = nb1.x; Bs[nb][lcol + 1][lrow + 64] = nb1.y;
        Bs[nb][lcol + 2][lrow + 64] = nb1.z; Bs[nb][lcol + 3][lrow + 64] = nb1.w;

        __syncthreads();      // single barrier per tile: separates write(buf^1)
        buf = nb;             // from next iteration's read(buf^1)
    }

    // epilogue
    float bia[8];
#pragma unroll
    for (int j = 0; j < 8; ++j) {
        int col = n0 + tx * 8 + j;
        bia[j] = b1[col] + (DUAL ? b2[col] : 0.f);
    }
#pragma unroll
    for (int r = 0; r < 8; ++r) {
        int row = m0 + ty * 8 + r;
        float v[8];
#pragma unroll
        for (int j = 0; j < 8; ++j) {
            v[j] = acc[r][j] + bia[j];
            if (RELU) v[j] = fmaxf(v[j], 0.f);
        }
        float* cp = &C[(size_t)row * N + n0 + tx * 8];
        *(float4*)&cp[0] = make_float4(v[0], v[1], v[2], v[3]);
        *(float4*)&cp[4] = make_float4(v[4], v[5], v[6], v[7]);
    }
}

// ---------------------------------------------------------------------------
// LSTM: one workgroup per (direction, batch). 512 threads; thread t owns gate
// row t of w_hh. Weights loaded via float4 TEMPORARIES + element assignment:
// no address-of on w[] -> SROA keeps all 128 floats in VGPRs (the R1/R3
// version took &w[k] -> scratch -> 34 GB of hidden reload traffic).
// Raw s_barrier with lgkmcnt-only drain: pre[] prefetch spans the whole step.
// ---------------------------------------------------------------------------
__device__ __forceinline__ float sigf(float x) { return 1.f / (1.f + expf(-x)); }

__global__ __launch_bounds__(512, 2)
void lstm_kernel(const float* __restrict__ preF, const float* __restrict__ preB,
                 const float* __restrict__ wF, const float* __restrict__ wB,
                 float* __restrict__ hF, float* __restrict__ hB)
{
    const int g = blockIdx.x;
    const int dir = g >> 5;          // 0 = fwd, 1 = bwd
    const int b = g & 31;
    const float* pre = dir ? preB : preF;
    const float* W   = dir ? wB : wF;
    float* hout      = dir ? hB : hF;

    const int t = threadIdx.x;       // 0..511 (gate index)

    float w[128];
#pragma unroll
    for (int k = 0; k < 128; k += 4) {
        float4 wv = *(const float4*)&W[(size_t)t * 128 + k];
        w[k + 0] = wv.x; w[k + 1] = wv.y; w[k + 2] = wv.z; w[k + 3] = wv.w;
    }

    __shared__ __align__(16) float h_s[128];
    __shared__ __align__(16) float g_s[512];

    float c_reg = 0.f;               // valid for t < 128 (owner of h/c lane t)
    if (t < 128) h_s[t] = 0.f;
    __syncthreads();

    const float* prow = pre + ((size_t)(dir ? (L_SEQ - 1) : 0) * BATCH + b) * GATES + t;
    const intptr_t pstep = (dir ? -(intptr_t)1 : (intptr_t)1) * (intptr_t)(BATCH * GATES);

    float pre_next = *prow;

    for (int step = 0; step < L_SEQ; ++step) {
        const int tt = dir ? (L_SEQ - 1 - step) : step;
        float pre_cur = pre_next;
        if (step + 1 < L_SEQ) prow += pstep;   // clamp at end (redundant reload, harmless)
        pre_next = *prow;                      // prefetch, stays in flight across barriers

        // matvec: 4 independent accumulator chains; h_s reads are wave-uniform
        // broadcasts (bank-conflict-free)
        float a0 = pre_cur, a1 = 0.f, a2 = 0.f, a3 = 0.f;
#pragma unroll
        for (int k = 0; k < 128; k += 4) {
            float4 hv = *(const float4*)&h_s[k];
            a0 = fmaf(w[k + 0], hv.x, a0);
            a1 = fmaf(w[k + 1], hv.y, a1);
            a2 = fmaf(w[k + 2], hv.z, a2);
            a3 = fmaf(w[k + 3], hv.w, a3);
        }
        g_s[t] = (a0 + a1) + (a2 + a3);

        // barrier A: share gates. LDS drain only; global prefetch stays in flight.
        asm volatile("s_waitcnt lgkmcnt(0)\n\ts_barrier" ::: "memory");

        float h_keep = 0.f;
        if (t < 128) {
            float iv = g_s[t];
            float fv = g_s[t + 128];
            float gv = g_s[t + 256];
            float ov = g_s[t + 384];
            c_reg = sigf(fv) * c_reg + sigf(iv) * tanhf(gv);
            h_keep = sigf(ov) * tanhf(c_reg);
            h_s[t] = h_keep;
        }

        // barrier B: share h. LDS drain only.
        asm volatile("s_waitcnt lgkmcnt(0)\n\ts_barrier" ::: "memory");

        // global store AFTER the barrier: overlaps the next step's matvec.
        if (t < 128)
            hout[((size_t)tt * BATCH + b) * HID + t] = h_keep;
    }
}

// ---------------------------------------------------------------------------
// Emit: emit[r][c] = dot(hf[r], crf_w[c][0:128]) + dot(hb[r], crf_w[c][128:256]) + crf_b[c]
// thread per (r, c);  r = l*B+b in [0, 65536), c in [0,4)
// ---------------------------------------------------------------------------
__global__ __launch_bounds__(256)
void emit_kernel(const float* __restrict__ hf, const float* __restrict__ hb,
                 const float* __restrict__ crf_w, const float* __restrict__ crf_b,
                 float* __restrict__ emit)
{
    const int idx = blockIdx.x * 256 + threadIdx.x;
    const int r = idx >> 2;
    const int c = idx & 3;
    const float* wf = &crf_w[c * 256];
    float acc = crf_b[c];
#pragma unroll 4
    for (int k = 0; k < 128; k += 4) {
        float4 hv = *(const float4*)&hf[(size_t)r * 128 + k];
        float4 wv = *(const float4*)&wf[k];
        acc = fmaf(hv.x, wv.x, acc); acc = fmaf(hv.y, wv.y, acc);
        acc = fmaf(hv.z, wv.z, acc); acc = fmaf(hv.w, wv.w, acc);
    }
#pragma unroll 4
    for (int k = 0; k < 128; k += 4) {
        float4 hv = *(const float4*)&hb[(size_t)r * 128 + k];
        float4 wv = *(const float4*)&wf[128 + k];
        acc = fmaf(hv.x, wv.x, acc); acc = fmaf(hv.y, wv.y, acc);
        acc = fmaf(hv.z, wv.z, acc); acc = fmaf(hv.w, wv.w, acc);
    }
    emit[idx] = acc;
}

// ---------------------------------------------------------------------------
// Viterbi + backtrace. 2 blocks x 64 threads (one wave). lane = b_loc*4 + i.
// Each block owns 16 batches. bp packed 2-bit x 4 states -> 1 byte per (t,b).
// ---------------------------------------------------------------------------
__global__ __launch_bounds__(64)
void viterbi_kernel(const float* __restrict__ emit, const float* __restrict__ trans,
                    float* __restrict__ out)
{
    const int lane = threadIdx.x;       // 0..63
    const int b_loc = lane >> 2;        // 0..15
    const int i = lane & 3;             // tag
    const int b = blockIdx.x * 16 + b_loc;
    const int base = lane & ~3;

    __shared__ uint8_t bp_s[L_SEQ * 16];
    __shared__ uint8_t tag_s[L_SEQ * 16];

    // per-lane transition row: T[i][j] for j=0..3
    float T0 = trans[i * 4 + 0];
    float T1 = trans[i * 4 + 1];
    float T2 = trans[i * 4 + 2];
    float T3 = trans[i * 4 + 3];
    float tstop = trans[STOP_TAG * 4 + i];

    float s = (i == START_TAG) ? 0.f : IMPOSSIBLE;

    float e_cur = emit[(size_t)0 * BATCH * NT + b * NT + i];
    for (int t = 0; t < L_SEQ; ++t) {
        float e_next = 0.f;
        if (t + 1 < L_SEQ)
            e_next = emit[(size_t)(t + 1) * BATCH * NT + b * NT + i];

        float s0 = __shfl(s, base + 0, 64);
        float s1 = __shfl(s, base + 1, 64);
        float s2 = __shfl(s, base + 2, 64);
        float s3 = __shfl(s, base + 3, 64);

        float a0 = s0 + T0, a1 = s1 + T1, a2 = s2 + T2, a3 = s3 + T3;
        float best = a0; int arg = 0;
        if (a1 > best) { best = a1; arg = 1; }
        if (a2 > best) { best = a2; arg = 2; }
        if (a3 > best) { best = a3; arg = 3; }

        s = best + e_cur;
        e_cur = e_next;

        int A0 = __shfl(arg, base + 0, 64);
        int A1 = __shfl(arg, base + 1, 64);
        int A2 = __shfl(arg, base + 2, 64);
        int A3 = __shfl(arg, base + 3, 64);
        if (i == 0)
            bp_s[t * 16 + b_loc] = (uint8_t)(A0 | (A1 << 2) | (A2 << 4) | (A3 << 6));
    }

    // final scores + argmax (first-max semantics)
    float f = s + tstop;
    float f0 = __shfl(f, base + 0, 64);
    float f1 = __shfl(f, base + 1, 64);
    float f2 = __shfl(f, base + 2, 64);
    float f3 = __shfl(f, base + 3, 64);
    float best = f0; int btag = 0;
    if (f1 > best) { best = f1; btag = 1; }
    if (f2 > best) { best = f2; btag = 2; }
    if (f3 > best) { best = f3; btag = 3; }

    if (i == 0) {
        out[b] = best;
        int tag = btag;
        tag_s[(L_SEQ - 1) * 16 + b_loc] = (uint8_t)tag;
        for (int t = L_SEQ - 1; t >= 1; --t) {
            uint8_t byte = bp_s[t * 16 + b_loc];
            tag = (byte >> (2 * tag)) & 3;
            tag_s[(t - 1) * 16 + b_loc] = (uint8_t)tag;
        }
    }
    __syncthreads();

    // coalesced tag writeout: out[32 + b*L + t]
    float* tout = out + BATCH;
    for (int bb = 0; bb < 16; ++bb) {
        int bg = blockIdx.x * 16 + bb;
        for (int t0 = lane; t0 < L_SEQ; t0 += 64)
            tout[(size_t)bg * L_SEQ + t0] = (float)tag_s[t0 * 16 + bb];
    }
}

// ---------------------------------------------------------------------------
extern "C" void kernel_launch(void* const* d_in, const int* in_sizes, int n_in,
                              void* d_out, int out_size, void* d_ws, size_t ws_size,
                              hipStream_t stream)
{
    const float* src    = (const float*)d_in[0];
    const float* fc1_w  = (const float*)d_in[1];
    const float* fc1_b  = (const float*)d_in[2];
    const float* w_ih_f = (const float*)d_in[3];
    const float* w_hh_f = (const float*)d_in[4];
    const float* b_ih_f = (const float*)d_in[5];
    const float* b_hh_f = (const float*)d_in[6];
    const float* w_ih_b = (const float*)d_in[7];
    const float* w_hh_b = (const float*)d_in[8];
    const float* b_ih_b = (const float*)d_in[9];
    const float* b_hh_b = (const float*)d_in[10];
    const float* crf_w  = (const float*)d_in[11];
    const float* crf_b  = (const float*)d_in[12];
    const float* trans  = (const float*)d_in[13];

    char* ws = (char*)d_ws;
    const size_t MB = 1024 * 1024;
    float* x    = (float*)(ws);              // 64 MB  [65536][256]
    float* preF = (float*)(ws + 64 * MB);    // 128 MB [65536][512]
    float* preB = (float*)(ws + 192 * MB);   // 128 MB [65536][512]
    float* hf   = (float*)(ws);              // 32 MB  (reuse x after pre GEMMs)
    float* hb   = (float*)(ws + 32 * MB);    // 32 MB
    float* emit = (float*)(ws + 64 * MB);    // 1 MB   (reuse preF after LSTM)

    const int M = L_SEQ * BATCH;  // 65536

    // FC1: x = relu(src @ fc1_w^T + fc1_b)
    {
        dim3 grid(M / 128, DENSE / 128);
        gemm_nt<true, false><<<grid, 256, 0, stream>>>(src, fc1_w, fc1_b, nullptr,
                                                       x, M, DENSE, D_IN);
    }
    // pre = x @ w_ih^T + (b_ih + b_hh)
    {
        dim3 grid(M / 128, GATES / 128);
        gemm_nt<false, true><<<grid, 256, 0, stream>>>(x, w_ih_f, b_ih_f, b_hh_f,
                                                       preF, M, GATES, DENSE);
        gemm_nt<false, true><<<grid, 256, 0, stream>>>(x, w_ih_b, b_ih_b, b_hh_b,
                                                       preB, M, GATES, DENSE);
    }
    // LSTM both directions (64 independent chains)
    lstm_kernel<<<64, 512, 0, stream>>>(preF, preB, w_hh_f, w_hh_b, hf, hb);

    // emit
    emit_kernel<<<(M * NT) / 256, 256, 0, stream>>>(hf, hb, crf_w, crf_b, emit);

    // viterbi + backtrace
    viterbi_kernel<<<2, 64, 0, stream>>>(emit, trans, (float*)d_out);
}

// Round 8
// 4163.953 us; speedup vs baseline: 1.1525x; 1.1525x over previous
//
#include <hip/hip_runtime.h>
#include <hip/hip_bf16.h>
#include <stdint.h>

#define L_SEQ 2048
#define BATCH 32
#define D_IN 1024
#define DENSE 256
#define HID 128
#define GATES 512   // 4*HID
#define NT 4
#define START_TAG 2
#define STOP_TAG 3
#define IMPOSSIBLE -10000.0f

// ---------------------------------------------------------------------------
// Tiled fp32 GEMM:  C[M,N] = act(A[M,K] * Bw[N,K]^T + bias1[n] (+ bias2[n]))
// 128x128 tile, BK=16, 256 threads, 8x8 microtile, double-buffered ping-pong,
// one barrier per K-tile.
// ---------------------------------------------------------------------------
template<bool RELU, bool DUAL>
__global__ __launch_bounds__(256)
void gemm_nt(const float* __restrict__ A, const float* __restrict__ Bw,
             const float* __restrict__ b1, const float* __restrict__ b2,
             float* __restrict__ C, int M, int N, int K)
{
    __shared__ __align__(16) float As[2][16][132];
    __shared__ __align__(16) float Bs[2][16][132];

    const int tid = threadIdx.x;
    const int tx = tid & 15;        // 0..15  -> N direction
    const int ty = tid >> 4;        // 0..15  -> M direction
    const int m0 = blockIdx.x * 128;
    const int n0 = blockIdx.y * 128;

    const int lrow = tid >> 2;          // 0..63
    const int lcol = (tid & 3) * 4;     // 0,4,8,12

    const float* aptr = &A[(size_t)(m0 + lrow) * K + lcol];
    const float* bptr = &Bw[(size_t)(n0 + lrow) * K + lcol];
    const size_t rstride = (size_t)64 * K;

    float acc[8][8];
#pragma unroll
    for (int i = 0; i < 8; ++i)
#pragma unroll
        for (int j = 0; j < 8; ++j) acc[i][j] = 0.f;

    // prologue: stage tile 0 into buf 0
    {
        float4 a0 = *(const float4*)(aptr);
        float4 a1 = *(const float4*)(aptr + rstride);
        float4 v0 = *(const float4*)(bptr);
        float4 v1 = *(const float4*)(bptr + rstride);
        As[0][lcol + 0][lrow] = a0.x; As[0][lcol + 1][lrow] = a0.y;
        As[0][lcol + 2][lrow] = a0.z; As[0][lcol + 3][lrow] = a0.w;
        As[0][lcol + 0][lrow + 64] = a1.x; As[0][lcol + 1][lrow + 64] = a1.y;
        As[0][lcol + 2][lrow + 64] = a1.z; As[0][lcol + 3][lrow + 64] = a1.w;
        Bs[0][lcol + 0][lrow] = v0.x; Bs[0][lcol + 1][lrow] = v0.y;
        Bs[0][lcol + 2][lrow] = v0.z; Bs[0][lcol + 3][lrow] = v0.w;
        Bs[0][lcol + 0][lrow + 64] = v1.x; Bs[0][lcol + 1][lrow + 64] = v1.y;
        Bs[0][lcol + 2][lrow + 64] = v1.z; Bs[0][lcol + 3][lrow + 64] = v1.w;
    }
    __syncthreads();

    int buf = 0;
    for (int k0 = 0; k0 < K; k0 += 16) {
        // issue next-tile loads NOW (redundant reload of last tile: harmless)
        const int kn = (k0 + 16 < K) ? (k0 + 16) : k0;
        float4 na0 = *(const float4*)(aptr + kn);
        float4 na1 = *(const float4*)(aptr + kn + rstride);
        float4 nb0 = *(const float4*)(bptr + kn);
        float4 nb1 = *(const float4*)(bptr + kn + rstride);

        // compute on current buffer (latency of na*/nb* hides under this)
#pragma unroll
        for (int kk = 0; kk < 16; ++kk) {
            float4 av0 = *(const float4*)&As[buf][kk][ty * 8];
            float4 av1 = *(const float4*)&As[buf][kk][ty * 8 + 4];
            float4 bv0 = *(const float4*)&Bs[buf][kk][tx * 8];
            float4 bv1 = *(const float4*)&Bs[buf][kk][tx * 8 + 4];
            float a[8], b[8];
            a[0] = av0.x; a[1] = av0.y; a[2] = av0.z; a[3] = av0.w;
            a[4] = av1.x; a[5] = av1.y; a[6] = av1.z; a[7] = av1.w;
            b[0] = bv0.x; b[1] = bv0.y; b[2] = bv0.z; b[3] = bv0.w;
            b[4] = bv1.x; b[5] = bv1.y; b[6] = bv1.z; b[7] = bv1.w;
#pragma unroll
            for (int i = 0; i < 8; ++i)
#pragma unroll
                for (int j = 0; j < 8; ++j)
                    acc[i][j] = fmaf(a[i], b[j], acc[i][j]);
        }

        // stage next tile into the other buffer (vmcnt drain lands here)
        const int nb = buf ^ 1;
        As[nb][lcol + 0][lrow] = na0.x; As[nb][lcol + 1][lrow] = na0.y;
        As[nb][lcol + 2][lrow] = na0.z; As[nb][lcol + 3][lrow] = na0.w;
        As[nb][lcol + 0][lrow + 64] = na1.x; As[nb][lcol + 1][lrow + 64] = na1.y;
        As[nb][lcol + 2][lrow + 64] = na1.z; As[nb][lcol + 3][lrow + 64] = na1.w;
        Bs[nb][lcol + 0][lrow] = nb0.x; Bs[nb][lcol + 1][lrow] = nb0.y;
        Bs[nb][lcol + 2][lrow] = nb0.z; Bs[nb][lcol + 3][lrow] = nb0.w;
        Bs[nb][lcol + 0][lrow + 64] = nb1.x; Bs[nb][lcol + 1][lrow + 64] = nb1.y;
        Bs[nb][lcol + 2][lrow + 64] = nb1.z; Bs[nb][lcol + 3][lrow + 64] = nb1.w;

        __syncthreads();      // single barrier per tile: separates write(buf^1)
        buf = nb;             // from next iteration's read(buf^1)
    }

    // epilogue
    float bia[8];
#pragma unroll
    for (int j = 0; j < 8; ++j) {
        int col = n0 + tx * 8 + j;
        bia[j] = b1[col] + (DUAL ? b2[col] : 0.f);
    }
#pragma unroll
    for (int r = 0; r < 8; ++r) {
        int row = m0 + ty * 8 + r;
        float v[8];
#pragma unroll
        for (int j = 0; j < 8; ++j) {
            v[j] = acc[r][j] + bia[j];
            if (RELU) v[j] = fmaxf(v[j], 0.f);
        }
        float* cp = &C[(size_t)row * N + n0 + tx * 8];
        *(float4*)&cp[0] = make_float4(v[0], v[1], v[2], v[3]);
        *(float4*)&cp[4] = make_float4(v[4], v[5], v[6], v[7]);
    }
}

// ---------------------------------------------------------------------------
// LSTM: one workgroup per (direction, batch). 512 threads; thread t owns gate
// row t of w_hh (weights in VGPR/AGPR, unified file).
//
// h-BROADCAST VIA VALU, NOT LDS (R6 fix): the old version had every thread
// re-read the full h vector from LDS -> 256 wave-uniform ds_read_b128 per
// CU per step ~ 3000 cy on the shared LDS pipe (the measured 3740 cy/step).
// Now each wave loads h ONCE coalesced (2 lane-distinct ds_read_b32), and
// h[k] is broadcast per-wave via v_readlane -> SGPR consumed directly by
// v_fma. LDS pipe: 16 ops/CU/step instead of 256.
// Chain order (k mod 4 -> a0..a3, (a0+a1)+(a2+a3)) identical -> bitwise
// same results as the passing R5 kernel.
// ---------------------------------------------------------------------------
__device__ __forceinline__ float sigf(float x) { return 1.f / (1.f + expf(-x)); }

__device__ __forceinline__ float bcast(float v, int lane) {
    return __int_as_float(__builtin_amdgcn_readlane(__float_as_int(v), lane));
}

__global__ __launch_bounds__(512, 2)
void lstm_kernel(const float* __restrict__ preF, const float* __restrict__ preB,
                 const float* __restrict__ wF, const float* __restrict__ wB,
                 float* __restrict__ hF, float* __restrict__ hB)
{
    const int g = blockIdx.x;
    const int dir = g >> 5;          // 0 = fwd, 1 = bwd
    const int b = g & 31;
    const float* pre = dir ? preB : preF;
    const float* W   = dir ? wB : wF;
    float* hout      = dir ? hB : hF;

    const int t = threadIdx.x;       // 0..511 (gate index)
    const int lane = t & 63;

    float w[128];
#pragma unroll
    for (int k = 0; k < 128; k += 4) {
        float4 wv = *(const float4*)&W[(size_t)t * 128 + k];
        w[k + 0] = wv.x; w[k + 1] = wv.y; w[k + 2] = wv.z; w[k + 3] = wv.w;
    }

    __shared__ __align__(16) float h_s[128];
    __shared__ __align__(16) float g_s[512];

    float c_reg = 0.f;               // valid for t < 128 (owner of h/c lane t)
    if (t < 128) h_s[t] = 0.f;
    __syncthreads();

    const float* prow = pre + ((size_t)(dir ? (L_SEQ - 1) : 0) * BATCH + b) * GATES + t;
    const intptr_t pstep = (dir ? -(intptr_t)1 : (intptr_t)1) * (intptr_t)(BATCH * GATES);

    float pre_next = *prow;

    for (int step = 0; step < L_SEQ; ++step) {
        const int tt = dir ? (L_SEQ - 1 - step) : step;
        float pre_cur = pre_next;
        if (step + 1 < L_SEQ) prow += pstep;   // clamp at end (redundant reload, harmless)
        pre_next = *prow;                      // prefetch, stays in flight across barriers

        // per-wave coalesced h load: lane l holds h[l] and h[64+l].
        // (reads h of the PREVIOUS step; ordered by barrier B of prev iter)
        float hreg0 = h_s[lane];
        float hreg1 = h_s[lane + 64];

        // matvec: 4 independent accumulator chains; h[k] broadcast via
        // v_readlane (VALU pipe) instead of uniform LDS reads.
        float a0 = pre_cur, a1 = 0.f, a2 = 0.f, a3 = 0.f;
#pragma unroll
        for (int k = 0; k < 128; k += 4) {
            const float src = (k < 64) ? hreg0 : hreg1;   // constant after unroll
            const int bl = k & 63;
            float h0 = bcast(src, bl + 0);
            float h1 = bcast(src, bl + 1);
            float h2 = bcast(src, bl + 2);
            float h3 = bcast(src, bl + 3);
            a0 = fmaf(w[k + 0], h0, a0);
            a1 = fmaf(w[k + 1], h1, a1);
            a2 = fmaf(w[k + 2], h2, a2);
            a3 = fmaf(w[k + 3], h3, a3);
        }
        g_s[t] = (a0 + a1) + (a2 + a3);

        // barrier A: share gates. LDS drain only; global prefetch stays in flight.
        asm volatile("s_waitcnt lgkmcnt(0)\n\ts_barrier" ::: "memory");

        float h_keep = 0.f;
        if (t < 128) {
            float iv = g_s[t];
            float fv = g_s[t + 128];
            float gv = g_s[t + 256];
            float ov = g_s[t + 384];
            c_reg = sigf(fv) * c_reg + sigf(iv) * tanhf(gv);
            h_keep = sigf(ov) * tanhf(c_reg);
            h_s[t] = h_keep;
        }

        // barrier B: share h. LDS drain only.
        asm volatile("s_waitcnt lgkmcnt(0)\n\ts_barrier" ::: "memory");

        // global store AFTER the barrier: overlaps the next step's matvec.
        if (t < 128)
            hout[((size_t)tt * BATCH + b) * HID + t] = h_keep;
    }
}

// ---------------------------------------------------------------------------
// Emit: emit[r][c] = dot(hf[r], crf_w[c][0:128]) + dot(hb[r], crf_w[c][128:256]) + crf_b[c]
// thread per (r, c);  r = l*B+b in [0, 65536), c in [0,4)
// ---------------------------------------------------------------------------
__global__ __launch_bounds__(256)
void emit_kernel(const float* __restrict__ hf, const float* __restrict__ hb,
                 const float* __restrict__ crf_w, const float* __restrict__ crf_b,
                 float* __restrict__ emit)
{
    const int idx = blockIdx.x * 256 + threadIdx.x;
    const int r = idx >> 2;
    const int c = idx & 3;
    const float* wf = &crf_w[c * 256];
    float acc = crf_b[c];
#pragma unroll 4
    for (int k = 0; k < 128; k += 4) {
        float4 hv = *(const float4*)&hf[(size_t)r * 128 + k];
        float4 wv = *(const float4*)&wf[k];
        acc = fmaf(hv.x, wv.x, acc); acc = fmaf(hv.y, wv.y, acc);
        acc = fmaf(hv.z, wv.z, acc); acc = fmaf(hv.w, wv.w, acc);
    }
#pragma unroll 4
    for (int k = 0; k < 128; k += 4) {
        float4 hv = *(const float4*)&hb[(size_t)r * 128 + k];
        float4 wv = *(const float4*)&wf[128 + k];
        acc = fmaf(hv.x, wv.x, acc); acc = fmaf(hv.y, wv.y, acc);
        acc = fmaf(hv.z, wv.z, acc); acc = fmaf(hv.w, wv.w, acc);
    }
    emit[idx] = acc;
}

// ---------------------------------------------------------------------------
// Viterbi + backtrace. 2 blocks x 64 threads (one wave). lane = b_loc*4 + i.
// Each block owns 16 batches. bp packed 2-bit x 4 states -> 1 byte per (t,b).
// ---------------------------------------------------------------------------
__global__ __launch_bounds__(64)
void viterbi_kernel(const float* __restrict__ emit, const float* __restrict__ trans,
                    float* __restrict__ out)
{
    const int lane = threadIdx.x;       // 0..63
    const int b_loc = lane >> 2;        // 0..15
    const int i = lane & 3;             // tag
    const int b = blockIdx.x * 16 + b_loc;
    const int base = lane & ~3;

    __shared__ uint8_t bp_s[L_SEQ * 16];
    __shared__ uint8_t tag_s[L_SEQ * 16];

    // per-lane transition row: T[i][j] for j=0..3
    float T0 = trans[i * 4 + 0];
    float T1 = trans[i * 4 + 1];
    float T2 = trans[i * 4 + 2];
    float T3 = trans[i * 4 + 3];
    float tstop = trans[STOP_TAG * 4 + i];

    float s = (i == START_TAG) ? 0.f : IMPOSSIBLE;

    float e_cur = emit[(size_t)0 * BATCH * NT + b * NT + i];
    for (int t = 0; t < L_SEQ; ++t) {
        float e_next = 0.f;
        if (t + 1 < L_SEQ)
            e_next = emit[(size_t)(t + 1) * BATCH * NT + b * NT + i];

        float s0 = __shfl(s, base + 0, 64);
        float s1 = __shfl(s, base + 1, 64);
        float s2 = __shfl(s, base + 2, 64);
        float s3 = __shfl(s, base + 3, 64);

        float a0 = s0 + T0, a1 = s1 + T1, a2 = s2 + T2, a3 = s3 + T3;
        float best = a0; int arg = 0;
        if (a1 > best) { best = a1; arg = 1; }
        if (a2 > best) { best = a2; arg = 2; }
        if (a3 > best) { best = a3; arg = 3; }

        s = best + e_cur;
        e_cur = e_next;

        int A0 = __shfl(arg, base + 0, 64);
        int A1 = __shfl(arg, base + 1, 64);
        int A2 = __shfl(arg, base + 2, 64);
        int A3 = __shfl(arg, base + 3, 64);
        if (i == 0)
            bp_s[t * 16 + b_loc] = (uint8_t)(A0 | (A1 << 2) | (A2 << 4) | (A3 << 6));
    }

    // final scores + argmax (first-max semantics)
    float f = s + tstop;
    float f0 = __shfl(f, base + 0, 64);
    float f1 = __shfl(f, base + 1, 64);
    float f2 = __shfl(f, base + 2, 64);
    float f3 = __shfl(f, base + 3, 64);
    float best = f0; int btag = 0;
    if (f1 > best) { best = f1; btag = 1; }
    if (f2 > best) { best = f2; btag = 2; }
    if (f3 > best) { best = f3; btag = 3; }

    if (i == 0) {
        out[b] = best;
        int tag = btag;
        tag_s[(L_SEQ - 1) * 16 + b_loc] = (uint8_t)tag;
        for (int t = L_SEQ - 1; t >= 1; --t) {
            uint8_t byte = bp_s[t * 16 + b_loc];
            tag = (byte >> (2 * tag)) & 3;
            tag_s[(t - 1) * 16 + b_loc] = (uint8_t)tag;
        }
    }
    __syncthreads();

    // coalesced tag writeout: out[32 + b*L + t]
    float* tout = out + BATCH;
    for (int bb = 0; bb < 16; ++bb) {
        int bg = blockIdx.x * 16 + bb;
        for (int t0 = lane; t0 < L_SEQ; t0 += 64)
            tout[(size_t)bg * L_SEQ + t0] = (float)tag_s[t0 * 16 + bb];
    }
}

// ---------------------------------------------------------------------------
extern "C" void kernel_launch(void* const* d_in, const int* in_sizes, int n_in,
                              void* d_out, int out_size, void* d_ws, size_t ws_size,
                              hipStream_t stream)
{
    const float* src    = (const float*)d_in[0];
    const float* fc1_w  = (const float*)d_in[1];
    const float* fc1_b  = (const float*)d_in[2];
    const float* w_ih_f = (const float*)d_in[3];
    const float* w_hh_f = (const float*)d_in[4];
    const float* b_ih_f = (const float*)d_in[5];
    const float* b_hh_f = (const float*)d_in[6];
    const float* w_ih_b = (const float*)d_in[7];
    const float* w_hh_b = (const float*)d_in[8];
    const float* b_ih_b = (const float*)d_in[9];
    const float* b_hh_b = (const float*)d_in[10];
    const float* crf_w  = (const float*)d_in[11];
    const float* crf_b  = (const float*)d_in[12];
    const float* trans  = (const float*)d_in[13];

    char* ws = (char*)d_ws;
    const size_t MB = 1024 * 1024;
    float* x    = (float*)(ws);              // 64 MB  [65536][256]
    float* preF = (float*)(ws + 64 * MB);    // 128 MB [65536][512]
    float* preB = (float*)(ws + 192 * MB);   // 128 MB [65536][512]
    float* hf   = (float*)(ws);              // 32 MB  (reuse x after pre GEMMs)
    float* hb   = (float*)(ws + 32 * MB);    // 32 MB
    float* emit = (float*)(ws + 64 * MB);    // 1 MB   (reuse preF after LSTM)

    const int M = L_SEQ * BATCH;  // 65536

    // FC1: x = relu(src @ fc1_w^T + fc1_b)
    {
        dim3 grid(M / 128, DENSE / 128);
        gemm_nt<true, false><<<grid, 256, 0, stream>>>(src, fc1_w, fc1_b, nullptr,
                                                       x, M, DENSE, D_IN);
    }
    // pre = x @ w_ih^T + (b_ih + b_hh)
    {
        dim3 grid(M / 128, GATES / 128);
        gemm_nt<false, true><<<grid, 256, 0, stream>>>(x, w_ih_f, b_ih_f, b_hh_f,
                                                       preF, M, GATES, DENSE);
        gemm_nt<false, true><<<grid, 256, 0, stream>>>(x, w_ih_b, b_ih_b, b_hh_b,
                                                       preB, M, GATES, DENSE);
    }
    // LSTM both directions (64 independent chains)
    lstm_kernel<<<64, 512, 0, stream>>>(preF, preB, w_hh_f, w_hh_b, hf, hb);

    // emit
    emit_kernel<<<(M * NT) / 256, 256, 0, stream>>>(hf, hb, crf_w, crf_b, emit);

    // viterbi + backtrace
    viterbi_kernel<<<2, 64, 0, stream>>>(emit, trans, (float*)d_out);
}